// Round 1
// baseline (745.096 us; speedup 1.0000x reference)
//
#include <hip/hip_runtime.h>
#include <hip/hip_bf16.h>

typedef unsigned short u16;
typedef __bf16 bf16x8 __attribute__((ext_vector_type(8)));
typedef float f32x4 __attribute__((ext_vector_type(4)));

#define DIM 2048
#define SEQ 2048
#define HEADS 16
#define DH 128
#define FUSED_OUT 18688   // 2048 q + 128 k + 128 v + 16384 ff
#define FF_INNER 8192
#define KOFF 2048
#define VOFF 2176
#define FFOFF 2304
#define AE_LD 10240       // 2048 attn + 8192 ffa concat-K for final GEMM

// ---- workspace layout (bytes). Total = 162,004,992 (~155 MB).
#define WS_XN   0
#define WS_WFT  8388608
#define WS_PROJ 84934656
#define WS_VT   161480704
#define WS_BTE  0
#define WS_AE   41943040

__device__ __forceinline__ float b2f(u16 u) {
  union { unsigned int i; float f; } c; c.i = ((unsigned int)u) << 16; return c.f;
}
__device__ __forceinline__ u16 f2b(float f) {  // RNE, matches np/jax bf16 cast
  union { float f; unsigned int i; } c; c.f = f;
  return (u16)((c.i + 0x7fffu + ((c.i >> 16) & 1u)) >> 16);
}
// async global->LDS, 16B per lane; LDS dest = wave-uniform base + lane*16
__device__ __forceinline__ void async16(void* lds, const void* g) {
  __builtin_amdgcn_global_load_lds((const __attribute__((address_space(1))) unsigned int*)g,
                                   (__attribute__((address_space(3))) unsigned int*)lds,
                                   16, 0, 0);
}

union U8 { uint4 v; u16 s[8]; };

// ---------------- LayerNorm: one block per row; f32 in -> bf16 out ----------------
__global__ void __launch_bounds__(256) ln_kernel(const float* __restrict__ x,
                                                 const float* __restrict__ gamma,
                                                 u16* __restrict__ xn) {
  const int row = blockIdx.x, tid = threadIdx.x;
  const int lane = tid & 63, wv = tid >> 6;
  float v[8], s1 = 0.f, s2 = 0.f;
  {
    float4 a0 = *(const float4*)(x + (size_t)row * DIM + tid * 8);
    float4 a1 = *(const float4*)(x + (size_t)row * DIM + tid * 8 + 4);
    v[0] = a0.x; v[1] = a0.y; v[2] = a0.z; v[3] = a0.w;
    v[4] = a1.x; v[5] = a1.y; v[6] = a1.z; v[7] = a1.w;
  }
#pragma unroll
  for (int i = 0; i < 8; ++i) { s1 += v[i]; s2 += v[i] * v[i]; }
#pragma unroll
  for (int off = 32; off > 0; off >>= 1) {
    s1 += __shfl_down(s1, off, 64);
    s2 += __shfl_down(s2, off, 64);
  }
  __shared__ float r1[4], r2[4];
  if (lane == 0) { r1[wv] = s1; r2[wv] = s2; }
  __syncthreads();
  s1 = r1[0] + r1[1] + r1[2] + r1[3];
  s2 = r2[0] + r2[1] + r2[2] + r2[3];
  const float inv = 1.0f / DIM;
  const float mu = s1 * inv;
  const float var = s2 * inv - mu * mu;
  const float rs = rsqrtf(var + 1e-5f);
  float4 g0 = *(const float4*)(gamma + tid * 8);
  float4 g1 = *(const float4*)(gamma + tid * 8 + 4);
  const float gm[8] = {g0.x, g0.y, g0.z, g0.w, g1.x, g1.y, g1.z, g1.w};
  U8 o;
#pragma unroll
  for (int i = 0; i < 8; ++i) o.s[i] = f2b((v[i] - mu) * rs * gm[i]);
  *(uint4*)(xn + (size_t)row * DIM + tid * 8) = o.v;
}

// ------- 64x64 transpose f32 -> bf16: out[c*ldout + r] = bf16(in[r*ldin + c]) -------
__global__ void __launch_bounds__(256) transpose_f2b64(const float* __restrict__ in,
                                                       u16* __restrict__ out,
                                                       int ldin, int ldout) {
  __shared__ u16 t[64][65];
  const int tx = threadIdx.x, ty = threadIdx.y;
  const int r0 = blockIdx.y * 64, c0 = blockIdx.x * 64;
#pragma unroll
  for (int i = 0; i < 16; ++i)
    t[ty + i * 4][tx] = f2b(in[(size_t)(r0 + ty + i * 4) * ldin + c0 + tx]);
  __syncthreads();
#pragma unroll
  for (int i = 0; i < 16; ++i)
    out[(size_t)(c0 + ty + i * 4) * ldout + r0 + tx] = t[tx][ty + i * 4];
}

// ------- merged w_attn/w_ff transpose into BtE (both ldin = DIM) -------
__global__ void __launch_bounds__(256) trans_wout64(const float* __restrict__ w_attn,
                                                    const float* __restrict__ w_ff,
                                                    u16* __restrict__ BtE) {
  __shared__ u16 t[64][65];
  const int tx = threadIdx.x, ty = threadIdx.y;
  const int c0 = blockIdx.x * 64;  // n (output row)
  const float* in; int r0, kout;
  if (blockIdx.y < 32) { in = w_attn; r0 = blockIdx.y * 64; kout = r0; }
  else { in = w_ff; r0 = (blockIdx.y - 32) * 64; kout = 2048 + r0; }
#pragma unroll
  for (int i = 0; i < 16; ++i)
    t[ty + i * 4][tx] = f2b(in[(size_t)(r0 + ty + i * 4) * DIM + c0 + tx]);
  __syncthreads();
#pragma unroll
  for (int i = 0; i < 16; ++i)
    BtE[(size_t)(c0 + ty + i * 4) * AE_LD + kout + tx] = t[tx][ty + i * 4];
}

// ------- 64x64 transpose bf16 -> bf16 (for V^T) -------
__global__ void __launch_bounds__(256) transpose_u16_64(const u16* __restrict__ in,
                                                        u16* __restrict__ out,
                                                        int ldin, int ldout) {
  __shared__ u16 t[64][65];
  const int tx = threadIdx.x, ty = threadIdx.y;
  const int r0 = blockIdx.y * 64, c0 = blockIdx.x * 64;
#pragma unroll
  for (int i = 0; i < 16; ++i)
    t[ty + i * 4][tx] = in[(size_t)(r0 + ty + i * 4) * ldin + c0 + tx];
  __syncthreads();
#pragma unroll
  for (int i = 0; i < 16; ++i)
    out[(size_t)(c0 + ty + i * 4) * ldout + r0 + tx] = t[tx][ty + i * 4];
}

// ---------------- GEMM: 256x256 8-phase counted-vmcnt (T2+T3+T4+T5) ----------------
// C(MxN) = A(MxK) @ Bt(NxK)^T, bf16 in, f32 acc. 512 thr = 8 waves (2M x 4N),
// per-wave 128x64 out. BK=64, LDS 128 KiB double-buffered, XOR-swizzled 16B blocks
// (block b of row r holds global block b^(r&7) -> ds_read_b128 conflict-free, same
// swizzle as verified 128^2 kernel). Schedule per K-tile t (4 phases, 16 MFMA each):
//  ph1: read B(all 8 frags)+A(mi0-1); stage (t+1).Ah1 -> other buf
//  ph2: read A(mi2-3);               stage (t+2).Bh0 -> cur buf (B last read ph1)
//  ph3: read A(mi4-5)[wm0:+mi6-7];   stage (t+2).Bh1 -> cur buf
//  ph4: [wm1: read A(mi6-7)];        stage (t+2).Ah0 -> cur buf; s_waitcnt vmcnt(6)
// vmcnt(6) = 3 half-tiles (2 loads each) in flight; never drained to 0 in the loop.
// Raw s_barrier (asm, memory clobber) so the compiler emits no vmcnt(0) drain.
// OUTMODE: 0 = bf16 store, 2 = f32 atomicAdd (split-K epilogue).
#define BAR()    asm volatile("s_barrier" ::: "memory")
#define LGKM0()  asm volatile("s_waitcnt lgkmcnt(0)" ::: "memory")
#define RA(mi, kk) (*(const bf16x8*)&sA[c][(wm * 128 + (mi) * 16 + lhalf) * 64 + ((((kk) * 4 + lgrp) ^ key) << 3)])
#define RB(ni, kk) (*(const bf16x8*)&sB[c][(wn * 64 + (ni) * 16 + lhalf) * 64 + ((((kk) * 4 + lgrp) ^ key) << 3)])
#define MFMA_Q(MB, AA)                                                   \
  _Pragma("unroll") for (int kk = 0; kk < 2; ++kk)                       \
  _Pragma("unroll") for (int u = 0; u < 2; ++u)                          \
  _Pragma("unroll") for (int ni = 0; ni < 4; ++ni)                       \
      acc[(MB) + u][ni] = __builtin_amdgcn_mfma_f32_16x16x32_bf16(       \
          AA[u][kk], bF[ni][kk], acc[(MB) + u][ni], 0, 0, 0);

__device__ __forceinline__ void stage_h(u16* lds, const u16* g, int ld,
                                        int wv, int srow, int scol) {
  // one 128x64 half-tile: 2 x (8 waves x 64 lanes x 16B); LDS base wave-uniform
  async16(lds + wv * 512,        g + (size_t)(wv * 8 + srow) * ld + scol);
  async16(lds + 4096 + wv * 512, g + (size_t)(64 + wv * 8 + srow) * ld + scol);
}

template <int OUTMODE>
__global__ void __launch_bounds__(512, 2) gemm8p(const u16* __restrict__ A,
                                                 const u16* __restrict__ Bt,
                                                 void* __restrict__ Cv,
                                                 int Ksz, int lda, int ldb, int ldc) {
  __shared__ alignas(16) u16 sA[2][256 * 64];
  __shared__ alignas(16) u16 sB[2][256 * 64];
  const int tid = threadIdx.x;
  const int lane = tid & 63, wv = tid >> 6;
  const int wm = wv >> 2, wn = wv & 3;          // 2M x 4N wave grid
  const int lhalf = lane & 15, lgrp = lane >> 4;
  const int key = lhalf & 7;
  const int srow = lane >> 3;                   // staging: row within 8-row chunk
  const int scol = ((lane & 7) ^ srow) << 3;    // pre-swizzled global col (u16)
  const int m0 = blockIdx.x * 256, n0 = blockIdx.y * 256;
  const int kbeg = blockIdx.z * Ksz;
  const int NT = Ksz >> 6;

  const u16* Abase = A + (size_t)m0 * lda + kbeg;
  const u16* Bbase = Bt + (size_t)n0 * ldb + kbeg;

  // ---- prologue: t0{Bh0,Bh1,Ah0,Ah1}->buf0, t1{Bh0,Bh1,Ah0}->buf1 (Ah1 in ph1 of t0)
  stage_h(&sB[0][0],    Bbase,                     ldb, wv, srow, scol);
  stage_h(&sB[0][8192], Bbase + (size_t)128 * ldb, ldb, wv, srow, scol);
  stage_h(&sA[0][0],    Abase,                     lda, wv, srow, scol);
  stage_h(&sA[0][8192], Abase + (size_t)128 * lda, lda, wv, srow, scol);
  asm volatile("s_waitcnt vmcnt(4)" ::: "memory");
  stage_h(&sB[1][0],    Bbase + 64,                     ldb, wv, srow, scol);
  stage_h(&sB[1][8192], Bbase + (size_t)128 * ldb + 64, ldb, wv, srow, scol);
  stage_h(&sA[1][0],    Abase + 64,                     lda, wv, srow, scol);
  asm volatile("s_waitcnt vmcnt(6)" ::: "memory");
  BAR();

  f32x4 acc[8][4];
  const f32x4 fzero = {0.f, 0.f, 0.f, 0.f};
#pragma unroll
  for (int i = 0; i < 8; ++i)
#pragma unroll
    for (int j = 0; j < 4; ++j) acc[i][j] = fzero;

  bf16x8 bF[4][2];   // B frags: read in ph1, live for the whole K-tile
  bf16x8 aF[2][2];   // current-phase A frags
  bf16x8 aX[2][2];   // wm0: mi6-7 prefetched in ph3 (Ah0 is re-staged in ph4)

  int t1w = 1;            // (t+1) mod NT (NT >= 3 for all call sites)
  int t2w = 2 % NT;       // (t+2) mod NT
  for (int t = 0; t < NT; ++t) {
    const int c = t & 1;
    // ---------- phase 1: 12 ds_reads; MFMA mi0-1 ----------
#pragma unroll
    for (int kk = 0; kk < 2; ++kk) {
      aF[0][kk] = RA(0, kk); aF[1][kk] = RA(1, kk);
#pragma unroll
      for (int ni = 0; ni < 4; ++ni) bF[ni][kk] = RB(ni, kk);
    }
    stage_h(&sA[c ^ 1][8192], Abase + (size_t)128 * lda + t1w * 64, lda, wv, srow, scol);
    asm volatile("s_waitcnt lgkmcnt(8)" ::: "memory");
    BAR(); LGKM0();
    __builtin_amdgcn_s_setprio(1);
    MFMA_Q(0, aF);
    __builtin_amdgcn_s_setprio(0);
    BAR();
    // ---------- phase 2: MFMA mi2-3 ----------
#pragma unroll
    for (int kk = 0; kk < 2; ++kk) { aF[0][kk] = RA(2, kk); aF[1][kk] = RA(3, kk); }
    stage_h(&sB[c][0], Bbase + t2w * 64, ldb, wv, srow, scol);
    BAR(); LGKM0();
    __builtin_amdgcn_s_setprio(1);
    MFMA_Q(2, aF);
    __builtin_amdgcn_s_setprio(0);
    BAR();
    // ---------- phase 3: MFMA mi4-5 (wm0 also prefetches mi6-7) ----------
#pragma unroll
    for (int kk = 0; kk < 2; ++kk) { aF[0][kk] = RA(4, kk); aF[1][kk] = RA(5, kk); }
    if (wm == 0) {
#pragma unroll
      for (int kk = 0; kk < 2; ++kk) { aX[0][kk] = RA(6, kk); aX[1][kk] = RA(7, kk); }
    }
    stage_h(&sB[c][8192], Bbase + (size_t)128 * ldb + t2w * 64, ldb, wv, srow, scol);
    BAR(); LGKM0();
    __builtin_amdgcn_s_setprio(1);
    MFMA_Q(4, aF);
    __builtin_amdgcn_s_setprio(0);
    BAR();
    // ---------- phase 4: MFMA mi6-7; counted vmcnt (once per K-tile) ----------
    if (wm != 0) {
#pragma unroll
      for (int kk = 0; kk < 2; ++kk) { aF[0][kk] = RA(6, kk); aF[1][kk] = RA(7, kk); }
    }
    stage_h(&sA[c][0], Abase + t2w * 64, lda, wv, srow, scol);
    asm volatile("s_waitcnt vmcnt(6)" ::: "memory");
    BAR(); LGKM0();
    __builtin_amdgcn_s_setprio(1);
    if (wm == 0) { MFMA_Q(6, aX); } else { MFMA_Q(6, aF); }
    __builtin_amdgcn_s_setprio(0);
    BAR();
    t1w = (t1w + 1 == NT) ? 0 : t1w + 1;
    t2w = (t2w + 1 == NT) ? 0 : t2w + 1;
  }
  asm volatile("s_waitcnt vmcnt(0)" ::: "memory");  // drain wrapped tail stages
  // C/D layout (verified m89/m91): col = lane&15, row = (lane>>4)*4 + reg
#pragma unroll
  for (int mi = 0; mi < 8; ++mi)
#pragma unroll
    for (int ni = 0; ni < 4; ++ni)
#pragma unroll
      for (int tt = 0; tt < 4; ++tt) {
        const int row = m0 + wm * 128 + mi * 16 + lgrp * 4 + tt;
        const int col = n0 + wn * 64 + ni * 16 + lhalf;
        if (OUTMODE == 0) ((u16*)Cv)[(size_t)row * ldc + col] = f2b(acc[mi][ni][tt]);
        else atomicAdd((float*)Cv + (size_t)row * ldc + col, acc[mi][ni][tt]);
      }
}

// ---------------- Flash MQA attention ----------------
__global__ void __launch_bounds__(256) attn_kernel(const u16* __restrict__ proj,
                                                   const u16* __restrict__ Vt,
                                                   u16* __restrict__ Ae) {
  const int h = blockIdx.y, qi = blockIdx.x;
  const int tid = threadIdx.x;
  const int lane = tid & 63, wv = tid >> 6;
  const int lhalf = lane & 15, lgrp = lane >> 4;
  const int key = lhalf & 7;

  __shared__ alignas(16) u16 Ks[128 * 128];       // K tile: [j][d], swizzled
  __shared__ alignas(16) u16 Vts[128 * 128];      // V^T tile: [d][j], swizzled
  __shared__ alignas(16) u16 Ps[4][16 * 128];     // per-wave P scratch, swizzled

  const int sr = lane >> 4;
  const int sb = lane & 15;

  bf16x8 aq[4];
  {
    const u16* gq = proj + (size_t)(qi * 64 + wv * 16 + lhalf) * FUSED_OUT + h * DH;
#pragma unroll
    for (int kk = 0; kk < 4; ++kk) aq[kk] = *(const bf16x8*)(gq + kk * 32 + lgrp * 8);
  }
  const f32x4 fzero = {0.f, 0.f, 0.f, 0.f};
  f32x4 o[8];
#pragma unroll
  for (int i = 0; i < 8; ++i) o[i] = fzero;
  float mrow[4] = {-__builtin_inff(), -__builtin_inff(), -__builtin_inff(), -__builtin_inff()};
  float lrow[4] = {0.f, 0.f, 0.f, 0.f};
  const float scale = 0.088388347648318447f;  // 128^-0.5
  const int jmax = (qi * 64 + 63) >> 7;

  for (int jt = 0; jt <= jmax; ++jt) {
    __syncthreads();
#pragma unroll
    for (int i = 0; i < 8; ++i) {
      const int ch = wv * 8 + i;
      const int row = ch * 4 + sr;
      const int gb = sb ^ (row & 7);
      async16(&Ks[ch * 512], proj + (size_t)(jt * 128 + row) * FUSED_OUT + KOFF + gb * 8);
      async16(&Vts[ch * 512], Vt + (size_t)row * SEQ + jt * 128 + gb * 8);
    }
    __syncthreads();
    f32x4 s[8];
#pragma unroll
    for (int sub = 0; sub < 8; ++sub) {
      f32x4 a = fzero;
#pragma unroll
      for (int kk = 0; kk < 4; ++kk) {
        bf16x8 bk = *(const bf16x8*)&Ks[(sub * 16 + lhalf) * 128 + (((kk * 4 + lgrp) ^ key) << 3)];
        a = __builtin_amdgcn_mfma_f32_16x16x32_bf16(aq[kk], bk, a, 0, 0, 0);
      }
      s[sub] = a;
    }
    const int row_g = qi * 64 + wv * 16 + lgrp * 4;
    const int col_b = jt * 128 + lhalf;
#pragma unroll
    for (int t = 0; t < 4; ++t) {
      float mx = -__builtin_inff();
#pragma unroll
      for (int sub = 0; sub < 8; ++sub) {
        float v = s[sub][t] * scale;
        if (col_b + sub * 16 > row_g + t) v = -__builtin_inff();
        s[sub][t] = v;
        mx = fmaxf(mx, v);
      }
      mx = fmaxf(mx, __shfl_xor(mx, 1, 64));
      mx = fmaxf(mx, __shfl_xor(mx, 2, 64));
      mx = fmaxf(mx, __shfl_xor(mx, 4, 64));
      mx = fmaxf(mx, __shfl_xor(mx, 8, 64));
      const float mnew = fmaxf(mrow[t], mx);
      const float alpha = __expf(mrow[t] - mnew);
      mrow[t] = mnew;
      float ls = 0.f;
#pragma unroll
      for (int sub = 0; sub < 8; ++sub) {
        const float p = __expf(s[sub][t] - mnew);
        s[sub][t] = p;
        ls += p;
      }
      ls += __shfl_xor(ls, 1, 64);
      ls += __shfl_xor(ls, 2, 64);
      ls += __shfl_xor(ls, 4, 64);
      ls += __shfl_xor(ls, 8, 64);
      lrow[t] = lrow[t] * alpha + ls;
      const int prow = lgrp * 4 + t;
      const int pkey = prow & 7;
#pragma unroll
      for (int sub = 0; sub < 8; ++sub) {
        o[sub][t] *= alpha;
        const int b = sub * 2 + (lhalf >> 3);
        Ps[wv][prow * 128 + ((b ^ pkey) << 3) + (lhalf & 7)] = f2b(s[sub][t]);
      }
    }
    asm volatile("s_waitcnt lgkmcnt(0)" ::: "memory");
#pragma unroll
    for (int kk = 0; kk < 4; ++kk) {
      bf16x8 ap = *(const bf16x8*)&Ps[wv][lhalf * 128 + (((kk * 4 + lgrp) ^ key) << 3)];
#pragma unroll
      for (int sub = 0; sub < 8; ++sub) {
        bf16x8 bv = *(const bf16x8*)&Vts[(sub * 16 + lhalf) * 128 + (((kk * 4 + lgrp) ^ key) << 3)];
        o[sub] = __builtin_amdgcn_mfma_f32_16x16x32_bf16(ap, bv, o[sub], 0, 0, 0);
      }
    }
  }
#pragma unroll
  for (int sub = 0; sub < 8; ++sub)
#pragma unroll
    for (int t = 0; t < 4; ++t) {
      const int row = qi * 64 + wv * 16 + lgrp * 4 + t;
      const int col = h * DH + sub * 16 + lhalf;
      Ae[(size_t)row * AE_LD + col] = f2b(o[sub][t] / lrow[t]);
    }
}

// ---------------- SiLU gate: Ae[:, 2048+j] = silu(gate)*ff_x ----------------
__global__ void __launch_bounds__(256) ffa_kernel(const u16* __restrict__ proj,
                                                  u16* __restrict__ Ae) {
  const size_t idx = (size_t)blockIdx.x * 256 + threadIdx.x;
  const size_t e = idx * 8;
  const int row = (int)(e >> 13);
  const int j = (int)(e & 8191);
  const u16* base = proj + (size_t)row * FUSED_OUT + FFOFF;
  U8 xr, gr, os;
  xr.v = *(const uint4*)(base + j);
  gr.v = *(const uint4*)(base + FF_INNER + j);
#pragma unroll
  for (int i = 0; i < 8; ++i) {
    const float g = b2f(gr.s[i]);
    const float sg = g / (1.f + __expf(-g));
    os.s[i] = f2b(sg * b2f(xr.s[i]));
  }
  *(uint4*)(Ae + (size_t)row * AE_LD + 2048 + j) = os.v;
}

extern "C" void kernel_launch(void* const* d_in, const int* in_sizes, int n_in,
                              void* d_out, int out_size, void* d_ws, size_t ws_size,
                              hipStream_t stream) {
  const float* x       = (const float*)d_in[0];
  const float* gamma   = (const float*)d_in[1];
  const float* w_fused = (const float*)d_in[2];
  const float* w_attn  = (const float*)d_in[3];
  const float* w_ff    = (const float*)d_in[4];
  float* out = (float*)d_out;
  char* ws = (char*)d_ws;
  u16* xn   = (u16*)(ws + WS_XN);
  u16* wfT  = (u16*)(ws + WS_WFT);
  u16* proj = (u16*)(ws + WS_PROJ);
  u16* Vt   = (u16*)(ws + WS_VT);
  u16* BtE  = (u16*)(ws + WS_BTE);   // aliases xn/wfT (dead after proj GEMM)
  u16* Ae   = (u16*)(ws + WS_AE);

  // zero d_out for the split-K atomic epilogue (harness poisons it with 0xAA)
  hipMemsetAsync(d_out, 0, (size_t)out_size * sizeof(float), stream);

  // Phase 1: LN + weight transpose(+cast) + fused projection GEMM (256^2 8-phase)
  ln_kernel<<<dim3(2048), dim3(256), 0, stream>>>(x, gamma, xn);
  transpose_f2b64<<<dim3(292, 32), dim3(64, 4), 0, stream>>>(w_fused, wfT, FUSED_OUT, DIM);
  gemm8p<0><<<dim3(8, 73, 1), dim3(512), 0, stream>>>(xn, wfT, proj, DIM, DIM, DIM, FUSED_OUT);

  // Phase 2: attention + gate, into concat-K activation buffer
  transpose_u16_64<<<dim3(2, 32), dim3(64, 4), 0, stream>>>(proj + VOFF, Vt, FUSED_OUT, SEQ);
  trans_wout64<<<dim3(32, 160), dim3(64, 4), 0, stream>>>(w_attn, w_ff, BtE);
  attn_kernel<<<dim3(32, 16), dim3(256), 0, stream>>>(proj, Vt, Ae);
  ffa_kernel<<<dim3(8192), dim3(256), 0, stream>>>(proj, Ae);

  // Phase 3: fused (attn_out + ff_out) via one concat-K split-K GEMM (256^2, z=4)
  gemm8p<2><<<dim3(8, 8, 4), dim3(512), 0, stream>>>(Ae, BtE, out, AE_LD / 4, AE_LD, AE_LD, DIM);
}